// Round 15
// baseline (126.111 us; speedup 1.0000x reference)
//
#include <hip/hip_runtime.h>
#include <hip/hip_bf16.h>

#define NB 1024
#define NH 256
#define EMB 128
#define TWOD 256
#define HID 256
#define CR 64               // rows per chunk
#define NCH 4               // chunks per batch element

typedef __attribute__((ext_vector_type(4))) float f32x4;
typedef __attribute__((ext_vector_type(8))) short bf16x8;

__device__ __forceinline__ unsigned short f2bf(float f) {
  union { float f; unsigned u; } v; v.f = f;
  unsigned u = v.u;
  unsigned r = (u + 0x7fffu + ((u >> 16) & 1u)) >> 16;
  return (unsigned short)r;
}

// W1 [d=256][n=256] fp32 -> W1T [n][d] bf16, coalesced both sides via LDS
// tile transpose (16 blocks of 64x64 tiles).
__global__ __launch_bounds__(256) void prep_w1t(const float* __restrict__ W1,
                                                unsigned short* __restrict__ W1T) {
  const int bx = blockIdx.x & 3;        // d-tile
  const int by = blockIdx.x >> 2;       // n-tile
  __shared__ float tile[64][65];        // +1 pad: conflict-free transpose read
  const int tr = threadIdx.x >> 6;      // 0..3
  const int tc = threadIdx.x & 63;      // 0..63
  #pragma unroll
  for (int i = 0; i < 16; ++i) {
    const int d = bx * 64 + i * 4 + tr;
    tile[i * 4 + tr][tc] = W1[(size_t)d * HID + by * 64 + tc];
  }
  __syncthreads();
  #pragma unroll
  for (int i = 0; i < 16; ++i) {
    const int n = by * 64 + i * 4 + tr;
    W1T[(size_t)n * TWOD + bx * 64 + tc] = f2bf(tile[tc][i * 4 + tr]);
  }
}

// 1024 blocks (1 per batch element), 512 threads = 8 waves, 4 chunks of 64 rows.
// Producer/consumer wave specialization:
//   waves 0-3: gather+fold+pack chunk t+1 into the spare panel buffer
//   waves 4-7: GEMM chunk t (64 rows x 64 cols per wave, kk-outer) + epilogue
//   wave 0 additionally folds chunk t-1's scores (masked exp + dot accumulate)
// Roles co-execute between barriers -> gather LLC latency hides under MFMA.
// Ledger: wave-uniform branches only; acc live range = one round; no fences.
__global__ __launch_bounds__(512, 4) void nais_main(
    const int* __restrict__ history, const int* __restrict__ target,
    const int* __restrict__ hregion, const int* __restrict__ tregion,
    const float* __restrict__ E_hist, const float* __restrict__ E_targ,
    const float* __restrict__ E_reg,
    const unsigned short* __restrict__ W1T, const float* __restrict__ b1,
    const float* __restrict__ w2, float* __restrict__ out)
{
  const int b = blockIdx.x;
  const int tid = threadIdx.x;
  const int lane = tid & 63;
  const int wave = tid >> 6;            // 0..3 producers, 4..7 consumers
  const int l15 = lane & 15;
  const int lhi = lane >> 4;
  const int l31 = lane & 31;
  const int halfsel = lane >> 5;        // 0: E_hist/E_targ half, 1: E_reg half

  __shared__ __align__(16) unsigned short inp[2][CR * 256];  // 2 x 32 KiB, swizzled
  __shared__ float score_parts[2][4][CR];                    // 2 KiB (chunk parity)
  __shared__ float dot_lds[NCH][CR];                         // 1 KiB
  __shared__ int items_lds[NCH][CR];                         // 1 KiB

  const int tgt_item = target[b];

  // role-specific constants
  f32x4 t;                              // producers
  const int* keysrc = history;
  const float* table = E_hist;
  float b1v[4], w2v[4];                 // consumers

  if (wave < 4) {
    const float* tsrc = halfsel ? (E_reg + (size_t)tregion[b] * EMB)
                                : (E_targ + (size_t)target[b] * EMB);
    t = *(const f32x4*)(tsrc + l31 * 4);
    keysrc = halfsel ? hregion : history;
    table = halfsel ? E_reg : E_hist;
  } else {
    const int col0 = (wave - 4) * 64;
    #pragma unroll
    for (int n = 0; n < 4; ++n) {
      b1v[n] = b1[col0 + n * 16 + l15];
      w2v[n] = w2[col0 + n * 16 + l15];
    }
  }

  // ---- producer: fill 16 rows of chunk c into panel buf (proven R12 code) ----
  auto FILL = [&](int c, int buf) {
    int key[16];
    #pragma unroll
    for (int s = 0; s < 16; ++s)
      key[s] = keysrc[b * NH + c * CR + wave * 16 + s];
    #pragma unroll
    for (int pass = 0; pass < 2; ++pass) {
      f32x4 vb[8];
      #pragma unroll
      for (int s = 0; s < 8; ++s)
        vb[s] = *(const f32x4*)(table + (size_t)key[pass * 8 + s] * EMB + l31 * 4);
      #pragma unroll
      for (int s = 0; s < 8; ++s) {
        const int row = wave * 16 + pass * 8 + s;     // 0..63
        if (lane == 0) items_lds[c][row] = key[pass * 8 + s];
        f32x4 v = vb[s] * t;
        float ds = v[0] + v[1] + v[2] + v[3];
        ds += __shfl_xor(ds, 1);
        ds += __shfl_xor(ds, 2);
        ds += __shfl_xor(ds, 4);
        ds += __shfl_xor(ds, 8);
        ds += __shfl_xor(ds, 16);
        ds += __shfl_xor(ds, 32);       // combine E_hist + E_reg halves
        if (lane == 0) dot_lds[c][row] = ds;
        float2 f01; f01.x = v[0]; f01.y = v[1];
        float2 f23; f23.x = v[2]; f23.y = v[3];
        union { __hip_bfloat162 h; unsigned u; } c0, c1;
        c0.h = __float22bfloat162_rn(f01);
        c1.h = __float22bfloat162_rn(f23);
        const int g = halfsel * 16 + (l31 >> 1);          // 16B granule 0..31
        const int gs = g ^ (row & 7) ^ ((g >> 3) & 3);    // swizzle (bijective/row)
        unsigned* dst = (unsigned*)&inp[buf][row * 256 + gs * 8 + (lane & 1) * 4];
        dst[0] = c0.u; dst[1] = c1.u;
      }
    }
  };

  float acc_e = 0.f, acc_ed = 0.f;      // wave 0 accumulators

  // ---- wave 0: fold one chunk's scores (64 lanes = 64 rows) ----
  auto P3 = [&](int c) {
    const int par = c & 1;
    const float sc = score_parts[par][0][lane] + score_parts[par][1][lane] +
                     score_parts[par][2][lane] + score_parts[par][3][lane];
    const float e = (items_lds[c][lane] != tgt_item) ? expf(sc) : 0.f;
    acc_e += e;
    acc_ed += e * dot_lds[c][lane];
  };

  // ---- consumer: GEMM chunk c (64 rows x this wave's 64 cols) ----
  auto GEMM = [&](int c, int buf) {
    const int col0 = (wave - 4) * 64;
    f32x4 acc[4][4];
    #pragma unroll
    for (int m = 0; m < 4; ++m)
      #pragma unroll
      for (int n = 0; n < 4; ++n)
        acc[m][n] = (f32x4){0.f, 0.f, 0.f, 0.f};

    #pragma unroll
    for (int kk = 0; kk < 8; ++kk) {
      bf16x8 bfr[4];
      #pragma unroll
      for (int n = 0; n < 4; ++n)
        bfr[n] = *(const bf16x8*)(W1T + (size_t)(col0 + n * 16 + l15) * TWOD + kk * 32 + lhi * 8);
      bf16x8 af[4];
      #pragma unroll
      for (int m = 0; m < 4; ++m) {
        const int row = m * 16 + l15;
        const int gk = kk * 4 + lhi;
        const int gs = gk ^ (row & 7) ^ ((gk >> 3) & 3);
        af[m] = *(const bf16x8*)(&inp[buf][row * 256 + gs * 8]);
      }
      __builtin_amdgcn_s_setprio(1);
      #pragma unroll
      for (int m = 0; m < 4; ++m)
        #pragma unroll
        for (int n = 0; n < 4; ++n)
          acc[m][n] = __builtin_amdgcn_mfma_f32_16x16x32_bf16(af[m], bfr[n], acc[m][n], 0, 0, 0);
      __builtin_amdgcn_s_setprio(0);
    }

    // epilogue: relu + b1, dot w2, 16-lane reduce -> score_parts[c&1][cw][row]
    const int cw = wave - 4;
    #pragma unroll
    for (int m = 0; m < 4; ++m) {
      #pragma unroll
      for (int r = 0; r < 4; ++r) {
        float p = 0.f;
        #pragma unroll
        for (int n = 0; n < 4; ++n) {
          float hv = acc[m][n][r] + b1v[n];   // C/D: col=lane&15, row=(lane>>4)*4+r
          hv = hv > 0.f ? hv : 0.f;
          p += hv * w2v[n];
        }
        p += __shfl_xor(p, 1);
        p += __shfl_xor(p, 2);
        p += __shfl_xor(p, 4);
        p += __shfl_xor(p, 8);
        if (l15 == 0) score_parts[c & 1][cw][m * 16 + lhi * 4 + r] = p;
      }
    }
  };

  // ---- pipeline ----
  if (wave < 4) FILL(0, 0);
  __syncthreads();

  #pragma unroll
  for (int tt = 0; tt < NCH; ++tt) {
    if (wave < 4) {
      if (tt < NCH - 1) FILL(tt + 1, (tt + 1) & 1);
      if (wave == 0 && tt >= 1) P3(tt - 1);
    } else {
      GEMM(tt, tt & 1);
    }
    __syncthreads();
  }

  // ---- tail: wave 0 folds last chunk, reduces, writes output ----
  if (wave == 0) {
    P3(NCH - 1);
    float se = acc_e, sd = acc_ed;
    #pragma unroll
    for (int off = 32; off >= 1; off >>= 1) {
      se += __shfl_xor(se, off);
      sd += __shfl_xor(sd, off);
    }
    if (lane == 0) {
      const float pred = (se > 0.f) ? (sd / sqrtf(se)) : 0.f;  // denom = sum^0.5
      out[b] = 1.f / (1.f + expf(-pred));
    }
  }
}

extern "C" void kernel_launch(void* const* d_in, const int* in_sizes, int n_in,
                              void* d_out, int out_size, void* d_ws, size_t ws_size,
                              hipStream_t stream) {
  const int* history = (const int*)d_in[0];
  const int* target  = (const int*)d_in[1];
  const int* hregion = (const int*)d_in[2];
  const int* tregion = (const int*)d_in[3];
  const float* E_hist = (const float*)d_in[4];
  const float* E_targ = (const float*)d_in[5];
  const float* E_reg  = (const float*)d_in[6];
  const float* W1 = (const float*)d_in[7];
  const float* b1 = (const float*)d_in[8];
  const float* w2 = (const float*)d_in[9];
  float* out = (float*)d_out;

  unsigned short* W1T = (unsigned short*)d_ws;   // 128 KB

  prep_w1t<<<16, 256, 0, stream>>>(W1, W1T);
  nais_main<<<NB, 512, 0, stream>>>(history, target, hregion, tregion,
                                    E_hist, E_targ, E_reg, W1T, b1, w2, out);
}

// Round 16
// 113.890 us; speedup vs baseline: 1.1073x; 1.1073x over previous
//
#include <hip/hip_runtime.h>
#include <hip/hip_bf16.h>

#define NB 1024
#define NH 256
#define EMB 128
#define TWOD 256
#define HID 256
#define ROWS 64             // history rows per block
#define BPB 4               // blocks per batch element
#define NBLK (NB * BPB)

typedef __attribute__((ext_vector_type(4))) float f32x4;
typedef __attribute__((ext_vector_type(8))) short bf16x8;

__device__ __forceinline__ unsigned short f2bf(float f) {
  union { float f; unsigned u; } v; v.f = f;
  unsigned u = v.u;
  unsigned r = (u + 0x7fffu + ((u >> 16) & 1u)) >> 16;
  return (unsigned short)r;
}

// W1 [d=256][n=256] fp32 -> W1T [n][d] bf16, coalesced both sides via LDS
// tile transpose (16 blocks of 64x64 tiles).
__global__ __launch_bounds__(256) void prep_w1t(const float* __restrict__ W1,
                                                unsigned short* __restrict__ W1T) {
  const int bx = blockIdx.x & 3;        // d-tile
  const int by = blockIdx.x >> 2;       // n-tile
  __shared__ float tile[64][65];        // +1 pad: conflict-free transpose read
  const int tr = threadIdx.x >> 6;      // 0..3
  const int tc = threadIdx.x & 63;      // 0..63
  #pragma unroll
  for (int i = 0; i < 16; ++i) {
    const int d = bx * 64 + i * 4 + tr;
    tile[i * 4 + tr][tc] = W1[(size_t)d * HID + by * 64 + tc];
  }
  __syncthreads();
  #pragma unroll
  for (int i = 0; i < 16; ++i) {
    const int n = by * 64 + i * 4 + tr;
    W1T[(size_t)n * TWOD + bx * 64 + tc] = f2bf(tile[tc][i * 4 + tr]);
  }
}

// 4096 blocks (4 per batch element), 256 threads = 4 waves, 64 rows per block.
// R14's proven per-wave code (2-pass spill-free gather, kk-outer GEMM) at a
// half-size block: LDS ~34 KB -> 4 INDEPENDENT blocks resident per CU
// (same 16 waves/CU, but 4-way phase decorrelation instead of 2-way).
// Each wave owns 64 hidden cols: acc[4][4] = 64 AGPR + 64 arch = 128 regs
// = exactly the 4-waves/SIMD tier (same as R12/R14 equilibrium).
__global__ __launch_bounds__(256, 4) void nais_main(
    const int* __restrict__ history, const int* __restrict__ target,
    const int* __restrict__ hregion, const int* __restrict__ tregion,
    const float* __restrict__ E_hist, const float* __restrict__ E_targ,
    const float* __restrict__ E_reg,
    const unsigned short* __restrict__ W1T, const float* __restrict__ b1,
    const float* __restrict__ w2,
    float* __restrict__ part_se, float* __restrict__ part_sd)
{
  const int blk = blockIdx.x;
  const int b = blk >> 2;
  const int r0 = (blk & 3) * ROWS;      // row offset within the 256-history
  const int tid = threadIdx.x;
  const int lane = tid & 63;
  const int wave = tid >> 6;            // 0..3
  const int l15 = lane & 15;
  const int lhi = lane >> 4;
  const int l31 = lane & 31;
  const int halfsel = lane >> 5;        // 0: E_hist/E_targ half, 1: E_reg half

  __shared__ __align__(16) unsigned short inp_lds[ROWS * 256];  // 32 KiB, swizzled
  __shared__ float dot_lds[ROWS];
  __shared__ int items_lds[ROWS];
  __shared__ float score_parts[4][ROWS];

  // per-lane target vector slice (4 floats), loaded directly
  const float* tsrc = halfsel ? (E_reg + (size_t)tregion[b] * EMB)
                              : (E_targ + (size_t)target[b] * EMB);
  const f32x4 t = *(const f32x4*)(tsrc + l31 * 4);
  const int tgt_item = target[b];

  const int* keysrc = halfsel ? hregion : history;
  const float* table = halfsel ? E_reg : E_hist;

  // ---- Phase 1: coalesced gather + multiply + bf16 tile + row sums ----
  {
    int key[16];
    #pragma unroll
    for (int s = 0; s < 16; ++s)
      key[s] = keysrc[b * NH + r0 + wave * 16 + s];

    #pragma unroll
    for (int pass = 0; pass < 2; ++pass) {
      f32x4 vb[8];
      #pragma unroll
      for (int s = 0; s < 8; ++s)
        vb[s] = *(const f32x4*)(table + (size_t)key[pass * 8 + s] * EMB + l31 * 4);

      #pragma unroll
      for (int s = 0; s < 8; ++s) {
        const int row = wave * 16 + pass * 8 + s;     // 0..63
        if (lane == 0) items_lds[row] = key[pass * 8 + s];  // lane 0: halfsel==0
        f32x4 v = vb[s] * t;
        float ds = v[0] + v[1] + v[2] + v[3];
        ds += __shfl_xor(ds, 1);
        ds += __shfl_xor(ds, 2);
        ds += __shfl_xor(ds, 4);
        ds += __shfl_xor(ds, 8);
        ds += __shfl_xor(ds, 16);
        ds += __shfl_xor(ds, 32);       // combine E_hist + E_reg halves
        if (lane == 0) dot_lds[row] = ds;

        float2 f01; f01.x = v[0]; f01.y = v[1];
        float2 f23; f23.x = v[2]; f23.y = v[3];
        __hip_bfloat162 p0 = __float22bfloat162_rn(f01);
        __hip_bfloat162 p1 = __float22bfloat162_rn(f23);
        union { __hip_bfloat162 h; unsigned u; } c0, c1;
        c0.h = p0; c1.h = p1;
        const int g = halfsel * 16 + (l31 >> 1);          // 16B granule 0..31
        const int gs = g ^ (row & 7) ^ ((g >> 3) & 3);    // swizzle (bijective/row)
        unsigned* dst = (unsigned*)&inp_lds[row * 256 + gs * 8 + (lane & 1) * 4];
        dst[0] = c0.u; dst[1] = c1.u;
      }
    }
  }
  __syncthreads();

  // ---- Phase 2: GEMM. wave owns cols [wave*64, wave*64+64); kk outer,
  //      4 bfr loads per kk feeding 16 MFMAs over the 64-row tile ----
  {
    const int col0 = wave * 64;
    float b1v[4], w2v[4];
    #pragma unroll
    for (int n = 0; n < 4; ++n) {
      const int colh = col0 + n * 16 + l15;
      b1v[n] = b1[colh];
      w2v[n] = w2[colh];
    }

    f32x4 acc[4][4];
    #pragma unroll
    for (int m = 0; m < 4; ++m)
      #pragma unroll
      for (int n = 0; n < 4; ++n)
        acc[m][n] = (f32x4){0.f, 0.f, 0.f, 0.f};

    #pragma unroll
    for (int kk = 0; kk < 8; ++kk) {
      bf16x8 bfr[4];
      #pragma unroll
      for (int n = 0; n < 4; ++n) {
        const int colh = col0 + n * 16 + l15;
        bfr[n] = *(const bf16x8*)(W1T + (size_t)colh * TWOD + kk * 32 + lhi * 8);
      }
      bf16x8 af[4];
      #pragma unroll
      for (int m = 0; m < 4; ++m) {
        const int row = m * 16 + l15;
        const int gk = kk * 4 + lhi;
        const int gs = gk ^ (row & 7) ^ ((gk >> 3) & 3);
        af[m] = *(const bf16x8*)(&inp_lds[row * 256 + gs * 8]);
      }
      __builtin_amdgcn_s_setprio(1);
      #pragma unroll
      for (int m = 0; m < 4; ++m)
        #pragma unroll
        for (int n = 0; n < 4; ++n)
          acc[m][n] = __builtin_amdgcn_mfma_f32_16x16x32_bf16(af[m], bfr[n], acc[m][n], 0, 0, 0);
      __builtin_amdgcn_s_setprio(0);
    }

    // epilogue: relu + b1, dot with w2, 16-lane reduce -> score_parts[wave][row]
    #pragma unroll
    for (int m = 0; m < 4; ++m) {
      #pragma unroll
      for (int r = 0; r < 4; ++r) {
        float p = 0.f;
        #pragma unroll
        for (int n = 0; n < 4; ++n) {
          float hv = acc[m][n][r] + b1v[n];   // C/D: col=lane&15, row=(lane>>4)*4+r
          hv = hv > 0.f ? hv : 0.f;
          p += hv * w2v[n];
        }
        p += __shfl_xor(p, 1);
        p += __shfl_xor(p, 2);
        p += __shfl_xor(p, 4);
        p += __shfl_xor(p, 8);
        if (l15 == 0) score_parts[wave][m * 16 + lhi * 4 + r] = p;
      }
    }
  }
  __syncthreads();

  // ---- Phase 3: masked exp + partial sums -> per-block ws slot ----
  if (wave == 0) {
    float sc = score_parts[0][lane] + score_parts[1][lane] +
               score_parts[2][lane] + score_parts[3][lane];
    float e = (items_lds[lane] != tgt_item) ? expf(sc) : 0.f;
    float ed = e * dot_lds[lane];
    #pragma unroll
    for (int off = 32; off >= 1; off >>= 1) {
      e += __shfl_xor(e, off);
      ed += __shfl_xor(ed, off);
    }
    if (lane == 0) {
      part_se[blk] = e;
      part_sd[blk] = ed;
    }
  }
}

__global__ __launch_bounds__(256) void finalize(const float* __restrict__ part_se,
                                                const float* __restrict__ part_sd,
                                                float* __restrict__ out) {
  const int b = blockIdx.x * 256 + threadIdx.x;
  if (b < NB) {
    float se = 0.f, sd = 0.f;
    #pragma unroll
    for (int i = 0; i < BPB; ++i) {
      se += part_se[b * BPB + i];
      sd += part_sd[b * BPB + i];
    }
    const float pred = (se > 0.f) ? (sd / sqrtf(se)) : 0.f;  // denom = sum^0.5
    out[b] = 1.f / (1.f + expf(-pred));
  }
}

extern "C" void kernel_launch(void* const* d_in, const int* in_sizes, int n_in,
                              void* d_out, int out_size, void* d_ws, size_t ws_size,
                              hipStream_t stream) {
  const int* history = (const int*)d_in[0];
  const int* target  = (const int*)d_in[1];
  const int* hregion = (const int*)d_in[2];
  const int* tregion = (const int*)d_in[3];
  const float* E_hist = (const float*)d_in[4];
  const float* E_targ = (const float*)d_in[5];
  const float* E_reg  = (const float*)d_in[6];
  const float* W1 = (const float*)d_in[7];
  const float* b1 = (const float*)d_in[8];
  const float* w2 = (const float*)d_in[9];
  float* out = (float*)d_out;

  char* p = (char*)d_ws;
  unsigned short* W1T = (unsigned short*)p;  p += (size_t)TWOD * HID * 2;   // 128 KB
  float* part_se = (float*)p;                p += (size_t)NBLK * 4;         // 16 KB
  float* part_sd = (float*)p;

  prep_w1t<<<16, 256, 0, stream>>>(W1, W1T);
  nais_main<<<NBLK, 256, 0, stream>>>(history, target, hregion, tregion,
                                      E_hist, E_targ, E_reg, W1T, b1, w2,
                                      part_se, part_sd);
  finalize<<<(NB + 255) / 256, 256, 0, stream>>>(part_se, part_sd, out);
}

// Round 17
// 86.094 us; speedup vs baseline: 1.4648x; 1.3229x over previous
//
#include <hip/hip_runtime.h>
#include <hip/hip_bf16.h>

#define NB 1024
#define NH 256
#define EMB 128
#define TWOD 256
#define HID 256
#define ROWS 128            // history rows per block
#define BPB 2               // blocks per batch element
#define NBLK (NB * BPB)

typedef __attribute__((ext_vector_type(4))) float f32x4;
typedef __attribute__((ext_vector_type(8))) short bf16x8;

__device__ __forceinline__ unsigned short f2bf(float f) {
  union { float f; unsigned u; } v; v.f = f;
  unsigned u = v.u;
  unsigned r = (u + 0x7fffu + ((u >> 16) & 1u)) >> 16;
  return (unsigned short)r;
}

// W1 [d=256][n=256] fp32 -> W1T [n][d] bf16, coalesced both sides via LDS
// tile transpose (16 blocks of 64x64 tiles).
__global__ __launch_bounds__(256) void prep_w1t(const float* __restrict__ W1,
                                                unsigned short* __restrict__ W1T) {
  const int bx = blockIdx.x & 3;        // d-tile
  const int by = blockIdx.x >> 2;       // n-tile
  __shared__ float tile[64][65];        // +1 pad: conflict-free transpose read
  const int tr = threadIdx.x >> 6;      // 0..3
  const int tc = threadIdx.x & 63;      // 0..63
  #pragma unroll
  for (int i = 0; i < 16; ++i) {
    const int d = bx * 64 + i * 4 + tr;
    tile[i * 4 + tr][tc] = W1[(size_t)d * HID + by * 64 + tc];
  }
  __syncthreads();
  #pragma unroll
  for (int i = 0; i < 16; ++i) {
    const int n = by * 64 + i * 4 + tr;
    W1T[(size_t)n * TWOD + bx * 64 + tc] = f2bf(tile[tc][i * 4 + tr]);
  }
}

// 2048 blocks (2 per batch element), 512 threads = 8 waves, 128 rows per block.
// R14 equilibrium (87.5us verified: 64 arch VGPR + 64 AGPR acc, kk-outer GEMM,
// 2-pass spill-free gather) with ONE contained change: the per-row 6-deep
// shuffle dot-reduction is REMOVED from the gather (was 96 DS ops + ~128 VALU
// on every wave's phase-1 critical path); dot_ht is instead recomputed from
// the bf16 LDS tile by all 8 waves in parallel in the epilogue shadow
// (16 rows/wave, 4 lanes/row, bank-rotated granule order).
__global__ __launch_bounds__(512, 4) void nais_main(
    const int* __restrict__ history, const int* __restrict__ target,
    const int* __restrict__ hregion, const int* __restrict__ tregion,
    const float* __restrict__ E_hist, const float* __restrict__ E_targ,
    const float* __restrict__ E_reg,
    const unsigned short* __restrict__ W1T, const float* __restrict__ b1,
    const float* __restrict__ w2,
    float* __restrict__ part_se, float* __restrict__ part_sd)
{
  const int blk = blockIdx.x;
  const int b = blk >> 1;
  const int r0 = (blk & 1) * ROWS;      // row offset within the 256-history
  const int tid = threadIdx.x;
  const int lane = tid & 63;
  const int wave = tid >> 6;            // 0..7
  const int l15 = lane & 15;
  const int lhi = lane >> 4;
  const int l31 = lane & 31;
  const int halfsel = lane >> 5;        // 0: E_hist/E_targ half, 1: E_reg half

  __shared__ __align__(16) unsigned short inp_lds[ROWS * 256];  // 64 KiB, swizzled
  __shared__ float dot_lds[ROWS];
  __shared__ int items_lds[ROWS];
  __shared__ float score_parts[8][ROWS];

  // per-lane target vector slice (4 floats), loaded directly
  const float* tsrc = halfsel ? (E_reg + (size_t)tregion[b] * EMB)
                              : (E_targ + (size_t)target[b] * EMB);
  const f32x4 t = *(const f32x4*)(tsrc + l31 * 4);
  const int tgt_item = target[b];

  const int* keysrc = halfsel ? hregion : history;
  const float* table = halfsel ? E_reg : E_hist;

  // ---- Phase 1: coalesced gather + multiply + bf16 tile (no dot here) ----
  {
    int key[16];
    #pragma unroll
    for (int s = 0; s < 16; ++s)
      key[s] = keysrc[b * NH + r0 + wave * 16 + s];

    #pragma unroll
    for (int pass = 0; pass < 2; ++pass) {
      f32x4 vb[8];
      #pragma unroll
      for (int s = 0; s < 8; ++s)
        vb[s] = *(const f32x4*)(table + (size_t)key[pass * 8 + s] * EMB + l31 * 4);

      #pragma unroll
      for (int s = 0; s < 8; ++s) {
        const int row = wave * 16 + pass * 8 + s;
        if (lane == 0) items_lds[row] = key[pass * 8 + s];  // lane 0: halfsel==0
        f32x4 v = vb[s] * t;
        float2 f01; f01.x = v[0]; f01.y = v[1];
        float2 f23; f23.x = v[2]; f23.y = v[3];
        __hip_bfloat162 p0 = __float22bfloat162_rn(f01);
        __hip_bfloat162 p1 = __float22bfloat162_rn(f23);
        union { __hip_bfloat162 h; unsigned u; } c0, c1;
        c0.h = p0; c1.h = p1;
        const int g = halfsel * 16 + (l31 >> 1);          // 16B granule 0..31
        const int gs = g ^ (row & 7) ^ ((g >> 3) & 3);    // swizzle (bijective/row)
        unsigned* dst = (unsigned*)&inp_lds[row * 256 + gs * 8 + (lane & 1) * 4];
        dst[0] = c0.u; dst[1] = c1.u;
      }
    }
  }
  __syncthreads();

  // ---- Phase 2: GEMM. wave owns cols [wave*32, wave*32+32); kk outer,
  //      both 64-row chunks inner -> each bfr load feeds 16 MFMAs ----
  {
    const int col0 = wave * 32;
    float b1v[2], w2v[2];
    #pragma unroll
    for (int n = 0; n < 2; ++n) {
      const int colh = col0 + n * 16 + l15;
      b1v[n] = b1[colh];
      w2v[n] = w2[colh];
    }

    f32x4 acc[2][4][2];
    #pragma unroll
    for (int c = 0; c < 2; ++c)
      #pragma unroll
      for (int m = 0; m < 4; ++m)
        #pragma unroll
        for (int n = 0; n < 2; ++n)
          acc[c][m][n] = (f32x4){0.f, 0.f, 0.f, 0.f};

    #pragma unroll
    for (int kk = 0; kk < 8; ++kk) {
      bf16x8 bfr[2];
      #pragma unroll
      for (int n = 0; n < 2; ++n) {
        const int colh = col0 + n * 16 + l15;
        bfr[n] = *(const bf16x8*)(W1T + (size_t)colh * TWOD + kk * 32 + lhi * 8);
      }
      bf16x8 af[2][4];
      #pragma unroll
      for (int c = 0; c < 2; ++c)
        #pragma unroll
        for (int m = 0; m < 4; ++m) {
          const int row = c * 64 + m * 16 + l15;
          const int gk = kk * 4 + lhi;
          const int gs = gk ^ (row & 7) ^ ((gk >> 3) & 3);
          af[c][m] = *(const bf16x8*)(&inp_lds[row * 256 + gs * 8]);
        }
      __builtin_amdgcn_s_setprio(1);
      #pragma unroll
      for (int c = 0; c < 2; ++c)
        #pragma unroll
        for (int m = 0; m < 4; ++m)
          #pragma unroll
          for (int n = 0; n < 2; ++n)
            acc[c][m][n] = __builtin_amdgcn_mfma_f32_16x16x32_bf16(af[c][m], bfr[n], acc[c][m][n], 0, 0, 0);
      __builtin_amdgcn_s_setprio(0);
    }

    // ---- dot_ht from the LDS tile: wave's own 16 rows, 4 lanes/row,
    //      rotated granule order (row&7 classes hit distinct banks) ----
    {
      const int drow = wave * 16 + (lane >> 2);   // 16 rows for this wave
      const int seg = lane & 3;                   // granule segment of 8
      float dsum = 0.f;
      #pragma unroll
      for (int j = 0; j < 8; ++j) {
        const int gidx = seg * 8 + ((j + drow) & 7);          // rotated
        const int gs = gidx ^ (drow & 7) ^ (seg & 3);         // same swizzle
        union { bf16x8 w; unsigned u[4]; } a;
        a.w = *(const bf16x8*)(&inp_lds[drow * 256 + gs * 8]);
        #pragma unroll
        for (int q = 0; q < 4; ++q) {
          union { unsigned u; float f; } lo, hi;
          lo.u = a.u[q] << 16;
          hi.u = a.u[q] & 0xFFFF0000u;
          dsum += lo.f + hi.f;
        }
      }
      dsum += __shfl_xor(dsum, 1);
      dsum += __shfl_xor(dsum, 2);
      if (seg == 0) dot_lds[drow] = dsum;
    }

    // epilogue: relu + b1, dot with w2, 16-lane reduce -> score_parts[wave][row]
    #pragma unroll
    for (int c = 0; c < 2; ++c) {
      #pragma unroll
      for (int m = 0; m < 4; ++m) {
        #pragma unroll
        for (int r = 0; r < 4; ++r) {
          float p = 0.f;
          #pragma unroll
          for (int n = 0; n < 2; ++n) {
            float hv = acc[c][m][n][r] + b1v[n];  // C/D: col=lane&15, row=(lane>>4)*4+r
            hv = hv > 0.f ? hv : 0.f;
            p += hv * w2v[n];
          }
          p += __shfl_xor(p, 1);
          p += __shfl_xor(p, 2);
          p += __shfl_xor(p, 4);
          p += __shfl_xor(p, 8);
          if (l15 == 0) score_parts[wave][c * 64 + m * 16 + lhi * 4 + r] = p;
        }
      }
    }
  }
  __syncthreads();

  // ---- Phase 3: masked exp + partial sums -> per-(block,wave) ws slots ----
  if (wave < 2) {
    const int lrow = wave * 64 + lane;
    float sc = 0.f;
    #pragma unroll
    for (int w = 0; w < 8; ++w) sc += score_parts[w][lrow];
    float e = (items_lds[lrow] != tgt_item) ? expf(sc) : 0.f;
    float ed = e * dot_lds[lrow];
    #pragma unroll
    for (int off = 32; off >= 1; off >>= 1) {
      e += __shfl_xor(e, off);
      ed += __shfl_xor(ed, off);
    }
    if (lane == 0) {
      part_se[blk * 2 + wave] = e;
      part_sd[blk * 2 + wave] = ed;
    }
  }
}

__global__ __launch_bounds__(256) void finalize(const float* __restrict__ part_se,
                                                const float* __restrict__ part_sd,
                                                float* __restrict__ out) {
  const int b = blockIdx.x * 256 + threadIdx.x;
  if (b < NB) {
    float se = 0.f, sd = 0.f;
    #pragma unroll
    for (int i = 0; i < BPB * 2; ++i) {
      se += part_se[b * BPB * 2 + i];
      sd += part_sd[b * BPB * 2 + i];
    }
    const float pred = (se > 0.f) ? (sd / sqrtf(se)) : 0.f;  // denom = sum^0.5
    out[b] = 1.f / (1.f + expf(-pred));
  }
}

extern "C" void kernel_launch(void* const* d_in, const int* in_sizes, int n_in,
                              void* d_out, int out_size, void* d_ws, size_t ws_size,
                              hipStream_t stream) {
  const int* history = (const int*)d_in[0];
  const int* target  = (const int*)d_in[1];
  const int* hregion = (const int*)d_in[2];
  const int* tregion = (const int*)d_in[3];
  const float* E_hist = (const float*)d_in[4];
  const float* E_targ = (const float*)d_in[5];
  const float* E_reg  = (const float*)d_in[6];
  const float* W1 = (const float*)d_in[7];
  const float* b1 = (const float*)d_in[8];
  const float* w2 = (const float*)d_in[9];
  float* out = (float*)d_out;

  char* p = (char*)d_ws;
  unsigned short* W1T = (unsigned short*)p;  p += (size_t)TWOD * HID * 2;   // 128 KB
  float* part_se = (float*)p;                p += (size_t)NBLK * 2 * 4;     // 16 KB
  float* part_sd = (float*)p;

  prep_w1t<<<16, 256, 0, stream>>>(W1, W1T);
  nais_main<<<NBLK, 512, 0, stream>>>(history, target, hregion, tregion,
                                      E_hist, E_targ, E_reg, W1T, b1, w2,
                                      part_se, part_sd);
  finalize<<<(NB + 255) / 256, 256, 0, stream>>>(part_se, part_sd, out);
}

// Round 18
// 85.691 us; speedup vs baseline: 1.4717x; 1.0047x over previous
//
#include <hip/hip_runtime.h>
#include <hip/hip_bf16.h>

#define NB 1024
#define NH 256
#define EMB 128
#define TWOD 256
#define HID 256
#define ROWS 128            // history rows per block
#define BPB 2               // blocks per batch element
#define NBLK (NB * BPB)

typedef __attribute__((ext_vector_type(4))) float f32x4;
typedef __attribute__((ext_vector_type(8))) short bf16x8;

__device__ __forceinline__ unsigned short f2bf(float f) {
  union { float f; unsigned u; } v; v.f = f;
  unsigned u = v.u;
  unsigned r = (u + 0x7fffu + ((u >> 16) & 1u)) >> 16;
  return (unsigned short)r;
}

// W1 [d=256][n=256] fp32 -> W1T [n][d] bf16, coalesced both sides via LDS
// tile transpose (16 blocks of 64x64 tiles).
__global__ __launch_bounds__(256) void prep_w1t(const float* __restrict__ W1,
                                                unsigned short* __restrict__ W1T) {
  const int bx = blockIdx.x & 3;        // d-tile
  const int by = blockIdx.x >> 2;       // n-tile
  __shared__ float tile[64][65];        // +1 pad: conflict-free transpose read
  const int tr = threadIdx.x >> 6;      // 0..3
  const int tc = threadIdx.x & 63;      // 0..63
  #pragma unroll
  for (int i = 0; i < 16; ++i) {
    const int d = bx * 64 + i * 4 + tr;
    tile[i * 4 + tr][tc] = W1[(size_t)d * HID + by * 64 + tc];
  }
  __syncthreads();
  #pragma unroll
  for (int i = 0; i < 16; ++i) {
    const int n = by * 64 + i * 4 + tr;
    W1T[(size_t)n * TWOD + bx * 64 + tc] = f2bf(tile[tc][i * 4 + tr]);
  }
}

// 2048 blocks (2 per batch element), 512 threads = 8 waves, 128 rows per block.
// R17 equilibrium with the gather replaced by zero-register DMA:
//  - E_hist fp32 rows DMA'd via global_load_lds into the tile rows (a 512B
//    fp32 hist row == one full 512B bf16 tile row, used as staging)
//  - E_reg half register-gathered in parallel (512KB table, L2-hot)
//  - per-wave vmcnt(0), in-place fold fp32->bf16 (x tgt) into swizzled
//    granules; reg half written after hist fold consumed bytes 256-511.
//  Wave owns its 16 rows end-to-end -> no extra barrier; GEMM/epilogue/dot/P3
//  byte-identical to R17.
__global__ __launch_bounds__(512, 4) void nais_main(
    const int* __restrict__ history, const int* __restrict__ target,
    const int* __restrict__ hregion, const int* __restrict__ tregion,
    const float* __restrict__ E_hist, const float* __restrict__ E_targ,
    const float* __restrict__ E_reg,
    const unsigned short* __restrict__ W1T, const float* __restrict__ b1,
    const float* __restrict__ w2,
    float* __restrict__ part_se, float* __restrict__ part_sd)
{
  const int blk = blockIdx.x;
  const int b = blk >> 1;
  const int r0 = (blk & 1) * ROWS;      // row offset within the 256-history
  const int tid = threadIdx.x;
  const int lane = tid & 63;
  const int wave = tid >> 6;            // 0..7
  const int l15 = lane & 15;
  const int lhi = lane >> 4;
  const int l31 = lane & 31;

  __shared__ __align__(16) unsigned short inp_lds[ROWS * 256];  // 64 KiB
  __shared__ float dot_lds[ROWS];
  __shared__ int keys_h[ROWS];
  __shared__ int keys_r[ROWS];
  __shared__ float score_parts[8][ROWS];

  const int tgt_item = target[b];

  // ---- P0: stage keys coalesced (also serve as item ids for P3) ----
  if (tid < ROWS) {
    keys_h[tid] = history[b * NH + r0 + tid];
  } else if (tid < 2 * ROWS) {
    keys_r[tid - ROWS] = hregion[b * NH + r0 + (tid - ROWS)];
  }
  __syncthreads();

  // ---- P1 (per-wave, no coupling): DMA hist fp32 + reg gather + fold ----
  {
    // (1) DMA: 8 instrs x 2 rows; lane L covers row +(L>>5), bytes (L&31)*16
    #pragma unroll
    for (int i = 0; i < 8; ++i) {
      const int wr0 = wave * 16 + i * 2;
      const int kh = keys_h[wr0 + (lane >> 5)];
      const float* src = E_hist + (size_t)kh * EMB + (lane & 31) * 4;
      __builtin_amdgcn_global_load_lds(
          (const __attribute__((address_space(1))) void*)src,
          (__attribute__((address_space(3))) void*)&inp_lds[wr0 * 256],
          16, 0, 0);
    }

    // (2) E_reg gather in parallel (L2-hot): 8 x 2 rows, f32x4 per lane
    const f32x4 t4r = *(const f32x4*)(E_reg + (size_t)tregion[b] * EMB + l31 * 4);
    f32x4 vb[8];
    #pragma unroll
    for (int i = 0; i < 8; ++i) {
      const int rr = wave * 16 + i * 2 + (lane >> 5);
      vb[i] = *(const f32x4*)(E_reg + (size_t)keys_r[rr] * EMB + l31 * 4);
    }

    // per-lane hist tgt pair (cols 2L, 2L+1)
    const float2 t2h = *(const float2*)(E_targ + (size_t)tgt_item * EMB + lane * 2);

    // (3) wait own DMAs (+ reg loads) — per-wave, no barrier
    asm volatile("s_waitcnt vmcnt(0)" ::: "memory");
    __builtin_amdgcn_sched_barrier(0);

    // (4) hist fold in place: lane reads fp32 pair (bytes 8L..8L+8 of row),
    //     writes bf16 pair to swizzled granule in bytes 0..255
    #pragma unroll
    for (int s = 0; s < 16; ++s) {
      const int row = wave * 16 + s;
      const char* rbase = (const char*)&inp_lds[row * 256];
      float2 f = *(const float2*)(rbase + lane * 8);
      float2 v; v.x = f.x * t2h.x; v.y = f.y * t2h.y;
      union { __hip_bfloat162 h; unsigned u; } c;
      c.h = __float22bfloat162_rn(v);
      const int g = lane >> 2;                          // granule 0..15
      const int gs = g ^ (row & 7) ^ ((g >> 3) & 3);    // swizzle (bijective/row)
      *(unsigned*)((char*)&inp_lds[row * 256] + gs * 16 + (lane & 3) * 4) = c.u;
    }

    // (5) reg fold: after hist fold consumed bytes 256..511 as fp32
    #pragma unroll
    for (int i = 0; i < 8; ++i) {
      const int row = wave * 16 + i * 2 + (lane >> 5);
      f32x4 v = vb[i] * t4r;
      float2 f01; f01.x = v[0]; f01.y = v[1];
      float2 f23; f23.x = v[2]; f23.y = v[3];
      union { __hip_bfloat162 h; unsigned u; } c0, c1;
      c0.h = __float22bfloat162_rn(f01);
      c1.h = __float22bfloat162_rn(f23);
      const int g = 16 + (l31 >> 1);                    // granule 16..31
      const int gs = g ^ (row & 7) ^ ((g >> 3) & 3);
      unsigned* dst = (unsigned*)((char*)&inp_lds[row * 256] + gs * 16 + (l31 & 1) * 8);
      dst[0] = c0.u; dst[1] = c1.u;
    }
  }
  __syncthreads();

  // ---- P2: GEMM. wave owns cols [wave*32, wave*32+32); kk outer,
  //      both 64-row chunks inner -> each bfr load feeds 16 MFMAs ----
  {
    const int col0 = wave * 32;
    float b1v[2], w2v[2];
    #pragma unroll
    for (int n = 0; n < 2; ++n) {
      const int colh = col0 + n * 16 + l15;
      b1v[n] = b1[colh];
      w2v[n] = w2[colh];
    }

    f32x4 acc[2][4][2];
    #pragma unroll
    for (int c = 0; c < 2; ++c)
      #pragma unroll
      for (int m = 0; m < 4; ++m)
        #pragma unroll
        for (int n = 0; n < 2; ++n)
          acc[c][m][n] = (f32x4){0.f, 0.f, 0.f, 0.f};

    #pragma unroll
    for (int kk = 0; kk < 8; ++kk) {
      bf16x8 bfr[2];
      #pragma unroll
      for (int n = 0; n < 2; ++n) {
        const int colh = col0 + n * 16 + l15;
        bfr[n] = *(const bf16x8*)(W1T + (size_t)colh * TWOD + kk * 32 + lhi * 8);
      }
      bf16x8 af[2][4];
      #pragma unroll
      for (int c = 0; c < 2; ++c)
        #pragma unroll
        for (int m = 0; m < 4; ++m) {
          const int row = c * 64 + m * 16 + l15;
          const int gk = kk * 4 + lhi;
          const int gs = gk ^ (row & 7) ^ ((gk >> 3) & 3);
          af[c][m] = *(const bf16x8*)(&inp_lds[row * 256 + gs * 8]);
        }
      __builtin_amdgcn_s_setprio(1);
      #pragma unroll
      for (int c = 0; c < 2; ++c)
        #pragma unroll
        for (int m = 0; m < 4; ++m)
          #pragma unroll
          for (int n = 0; n < 2; ++n)
            acc[c][m][n] = __builtin_amdgcn_mfma_f32_16x16x32_bf16(af[c][m], bfr[n], acc[c][m][n], 0, 0, 0);
      __builtin_amdgcn_s_setprio(0);
    }

    // ---- dot_ht from the LDS tile (R17): wave's own 16 rows, 4 lanes/row ----
    {
      const int drow = wave * 16 + (lane >> 2);
      const int seg = lane & 3;
      float dsum = 0.f;
      #pragma unroll
      for (int j = 0; j < 8; ++j) {
        const int gidx = seg * 8 + ((j + drow) & 7);          // rotated
        const int gs = gidx ^ (drow & 7) ^ (seg & 3);         // same swizzle
        union { bf16x8 w; unsigned u[4]; } a;
        a.w = *(const bf16x8*)(&inp_lds[drow * 256 + gs * 8]);
        #pragma unroll
        for (int q = 0; q < 4; ++q) {
          union { unsigned u; float f; } lo, hi;
          lo.u = a.u[q] << 16;
          hi.u = a.u[q] & 0xFFFF0000u;
          dsum += lo.f + hi.f;
        }
      }
      dsum += __shfl_xor(dsum, 1);
      dsum += __shfl_xor(dsum, 2);
      if (seg == 0) dot_lds[drow] = dsum;
    }

    // epilogue: relu + b1, dot with w2, 16-lane reduce -> score_parts[wave][row]
    #pragma unroll
    for (int c = 0; c < 2; ++c) {
      #pragma unroll
      for (int m = 0; m < 4; ++m) {
        #pragma unroll
        for (int r = 0; r < 4; ++r) {
          float p = 0.f;
          #pragma unroll
          for (int n = 0; n < 2; ++n) {
            float hv = acc[c][m][n][r] + b1v[n];  // C/D: col=lane&15, row=(lane>>4)*4+r
            hv = hv > 0.f ? hv : 0.f;
            p += hv * w2v[n];
          }
          p += __shfl_xor(p, 1);
          p += __shfl_xor(p, 2);
          p += __shfl_xor(p, 4);
          p += __shfl_xor(p, 8);
          if (l15 == 0) score_parts[wave][c * 64 + m * 16 + lhi * 4 + r] = p;
        }
      }
    }
  }
  __syncthreads();

  // ---- P3: masked exp + partial sums -> per-(block,wave) ws slots ----
  if (wave < 2) {
    const int lrow = wave * 64 + lane;
    float sc = 0.f;
    #pragma unroll
    for (int w = 0; w < 8; ++w) sc += score_parts[w][lrow];
    float e = (keys_h[lrow] != tgt_item) ? expf(sc) : 0.f;
    float ed = e * dot_lds[lrow];
    #pragma unroll
    for (int off = 32; off >= 1; off >>= 1) {
      e += __shfl_xor(e, off);
      ed += __shfl_xor(ed, off);
    }
    if (lane == 0) {
      part_se[blk * 2 + wave] = e;
      part_sd[blk * 2 + wave] = ed;
    }
  }
}

__global__ __launch_bounds__(256) void finalize(const float* __restrict__ part_se,
                                                const float* __restrict__ part_sd,
                                                float* __restrict__ out) {
  const int b = blockIdx.x * 256 + threadIdx.x;
  if (b < NB) {
    float se = 0.f, sd = 0.f;
    #pragma unroll
    for (int i = 0; i < BPB * 2; ++i) {
      se += part_se[b * BPB * 2 + i];
      sd += part_sd[b * BPB * 2 + i];
    }
    const float pred = (se > 0.f) ? (sd / sqrtf(se)) : 0.f;  // denom = sum^0.5
    out[b] = 1.f / (1.f + expf(-pred));
  }
}

extern "C" void kernel_launch(void* const* d_in, const int* in_sizes, int n_in,
                              void* d_out, int out_size, void* d_ws, size_t ws_size,
                              hipStream_t stream) {
  const int* history = (const int*)d_in[0];
  const int* target  = (const int*)d_in[1];
  const int* hregion = (const int*)d_in[2];
  const int* tregion = (const int*)d_in[3];
  const float* E_hist = (const float*)d_in[4];
  const float* E_targ = (const float*)d_in[5];
  const float* E_reg  = (const float*)d_in[6];
  const float* W1 = (const float*)d_in[7];
  const float* b1 = (const float*)d_in[8];
  const float* w2 = (const float*)d_in[9];
  float* out = (float*)d_out;

  char* p = (char*)d_ws;
  unsigned short* W1T = (unsigned short*)p;  p += (size_t)TWOD * HID * 2;   // 128 KB
  float* part_se = (float*)p;                p += (size_t)NBLK * 2 * 4;     // 16 KB
  float* part_sd = (float*)p;

  prep_w1t<<<16, 256, 0, stream>>>(W1, W1T);
  nais_main<<<NBLK, 512, 0, stream>>>(history, target, hregion, tregion,
                                      E_hist, E_targ, E_reg, W1T, b1, w2,
                                      part_se, part_sd);
  finalize<<<(NB + 255) / 256, 256, 0, stream>>>(part_se, part_sd, out);
}

// Round 19
// 84.423 us; speedup vs baseline: 1.4938x; 1.0150x over previous
//
#include <hip/hip_runtime.h>
#include <hip/hip_bf16.h>

#define NB 1024
#define NH 256
#define EMB 128
#define TWOD 256
#define HID 256
#define ROWS 128            // history rows per block
#define BPB 2               // blocks per batch element
#define NBLK (NB * BPB)

typedef __attribute__((ext_vector_type(4))) float f32x4;
typedef __attribute__((ext_vector_type(8))) short bf16x8;

__device__ __forceinline__ unsigned short f2bf(float f) {
  union { float f; unsigned u; } v; v.f = f;
  unsigned u = v.u;
  unsigned r = (u + 0x7fffu + ((u >> 16) & 1u)) >> 16;
  return (unsigned short)r;
}

// W1 [d=256][n=256] fp32 -> W1T [n][d] bf16, coalesced both sides via LDS
// tile transpose (16 blocks of 64x64 tiles).
__global__ __launch_bounds__(256) void prep_w1t(const float* __restrict__ W1,
                                                unsigned short* __restrict__ W1T) {
  const int bx = blockIdx.x & 3;        // d-tile
  const int by = blockIdx.x >> 2;       // n-tile
  __shared__ float tile[64][65];        // +1 pad: conflict-free transpose read
  const int tr = threadIdx.x >> 6;      // 0..3
  const int tc = threadIdx.x & 63;      // 0..63
  #pragma unroll
  for (int i = 0; i < 16; ++i) {
    const int d = bx * 64 + i * 4 + tr;
    tile[i * 4 + tr][tc] = W1[(size_t)d * HID + by * 64 + tc];
  }
  __syncthreads();
  #pragma unroll
  for (int i = 0; i < 16; ++i) {
    const int n = by * 64 + i * 4 + tr;
    W1T[(size_t)n * TWOD + bx * 64 + tc] = f2bf(tile[tc][i * 4 + tr]);
  }
}

// 2048 blocks (2 per batch element), 512 threads = 8 waves, 128 rows per block.
// R18 structure (DMA hist gather + parallel reg gather + in-place fold) with
// the key staging moved to the SCALAR pipe: row keys are wave-uniform, so
// with wave_s = readfirstlane(wave) they compile to s_load_dword (SMEM,
// zero VGPR cost). Deletes the keys-LDS arrays, the P0 phase, and its
// barrier — one serial LLC round trip off every wave's critical path.
__global__ __launch_bounds__(512, 4) void nais_main(
    const int* __restrict__ history, const int* __restrict__ target,
    const int* __restrict__ hregion, const int* __restrict__ tregion,
    const float* __restrict__ E_hist, const float* __restrict__ E_targ,
    const float* __restrict__ E_reg,
    const unsigned short* __restrict__ W1T, const float* __restrict__ b1,
    const float* __restrict__ w2,
    float* __restrict__ part_se, float* __restrict__ part_sd)
{
  const int blk = blockIdx.x;
  const int b = blk >> 1;
  const int r0 = (blk & 1) * ROWS;      // row offset within the 256-history
  const int tid = threadIdx.x;
  const int lane = tid & 63;
  const int wave = tid >> 6;            // 0..7
  const int wave_s = __builtin_amdgcn_readfirstlane(wave);  // provably scalar
  const int l15 = lane & 15;
  const int lhi = lane >> 4;
  const int l31 = lane & 31;

  __shared__ __align__(16) unsigned short inp_lds[ROWS * 256];  // 64 KiB
  __shared__ float dot_lds[ROWS];
  __shared__ float score_parts[8][ROWS];

  const int tgt_item = target[b];

  // ---- P1 (per-wave, no coupling): DMA hist fp32 + reg gather + fold ----
  {
    const int rsel = lane >> 5;         // which row of each 2-row pair

    // (1) DMA: 8 instrs x 2 rows; keys are scalar (s_load), lane L covers
    //     row +(L>>5), bytes (L&31)*16 of the 512B fp32 row
    #pragma unroll
    for (int i = 0; i < 8; ++i) {
      const int wr0 = wave_s * 16 + i * 2;
      const int kh0 = history[b * NH + r0 + wr0];       // s_load_dword
      const int kh1 = history[b * NH + r0 + wr0 + 1];   // s_load_dword
      const int kh = rsel ? kh1 : kh0;
      const float* src = E_hist + (size_t)kh * EMB + (lane & 31) * 4;
      __builtin_amdgcn_global_load_lds(
          (const __attribute__((address_space(1))) void*)src,
          (__attribute__((address_space(3))) void*)&inp_lds[wr0 * 256],
          16, 0, 0);
    }

    // (2) E_reg gather in parallel (L2-hot): scalar keys, f32x4 per lane
    const f32x4 t4r = *(const f32x4*)(E_reg + (size_t)tregion[b] * EMB + l31 * 4);
    f32x4 vb[8];
    #pragma unroll
    for (int i = 0; i < 8; ++i) {
      const int wr0 = wave_s * 16 + i * 2;
      const int kr0 = hregion[b * NH + r0 + wr0];       // s_load_dword
      const int kr1 = hregion[b * NH + r0 + wr0 + 1];   // s_load_dword
      const int kr = rsel ? kr1 : kr0;
      vb[i] = *(const f32x4*)(E_reg + (size_t)kr * EMB + l31 * 4);
    }

    // per-lane hist tgt pair (cols 2L, 2L+1)
    const float2 t2h = *(const float2*)(E_targ + (size_t)tgt_item * EMB + lane * 2);

    // (3) wait own DMAs (+ reg loads) — per-wave, no barrier
    asm volatile("s_waitcnt vmcnt(0)" ::: "memory");
    __builtin_amdgcn_sched_barrier(0);

    // (4) hist fold in place: lane reads fp32 pair (bytes 8L..8L+8 of row),
    //     writes bf16 pair to swizzled granule in bytes 0..255
    #pragma unroll
    for (int s = 0; s < 16; ++s) {
      const int row = wave_s * 16 + s;
      const char* rbase = (const char*)&inp_lds[row * 256];
      float2 f = *(const float2*)(rbase + lane * 8);
      float2 v; v.x = f.x * t2h.x; v.y = f.y * t2h.y;
      union { __hip_bfloat162 h; unsigned u; } c;
      c.h = __float22bfloat162_rn(v);
      const int g = lane >> 2;                          // granule 0..15
      const int gs = g ^ (row & 7) ^ ((g >> 3) & 3);    // swizzle (bijective/row)
      *(unsigned*)((char*)&inp_lds[row * 256] + gs * 16 + (lane & 3) * 4) = c.u;
    }

    // (5) reg fold: after hist fold consumed bytes 256..511 as fp32
    #pragma unroll
    for (int i = 0; i < 8; ++i) {
      const int row = wave_s * 16 + i * 2 + rsel;
      f32x4 v = vb[i] * t4r;
      float2 f01; f01.x = v[0]; f01.y = v[1];
      float2 f23; f23.x = v[2]; f23.y = v[3];
      union { __hip_bfloat162 h; unsigned u; } c0, c1;
      c0.h = __float22bfloat162_rn(f01);
      c1.h = __float22bfloat162_rn(f23);
      const int g = 16 + (l31 >> 1);                    // granule 16..31
      const int gs = g ^ (row & 7) ^ ((g >> 3) & 3);
      unsigned* dst = (unsigned*)((char*)&inp_lds[row * 256] + gs * 16 + (l31 & 1) * 8);
      dst[0] = c0.u; dst[1] = c1.u;
    }
  }
  __syncthreads();

  // ---- P2: GEMM. wave owns cols [wave*32, wave*32+32); kk outer,
  //      both 64-row chunks inner -> each bfr load feeds 16 MFMAs ----
  {
    const int col0 = wave * 32;
    float b1v[2], w2v[2];
    #pragma unroll
    for (int n = 0; n < 2; ++n) {
      const int colh = col0 + n * 16 + l15;
      b1v[n] = b1[colh];
      w2v[n] = w2[colh];
    }

    f32x4 acc[2][4][2];
    #pragma unroll
    for (int c = 0; c < 2; ++c)
      #pragma unroll
      for (int m = 0; m < 4; ++m)
        #pragma unroll
        for (int n = 0; n < 2; ++n)
          acc[c][m][n] = (f32x4){0.f, 0.f, 0.f, 0.f};

    #pragma unroll
    for (int kk = 0; kk < 8; ++kk) {
      bf16x8 bfr[2];
      #pragma unroll
      for (int n = 0; n < 2; ++n) {
        const int colh = col0 + n * 16 + l15;
        bfr[n] = *(const bf16x8*)(W1T + (size_t)colh * TWOD + kk * 32 + lhi * 8);
      }
      bf16x8 af[2][4];
      #pragma unroll
      for (int c = 0; c < 2; ++c)
        #pragma unroll
        for (int m = 0; m < 4; ++m) {
          const int row = c * 64 + m * 16 + l15;
          const int gk = kk * 4 + lhi;
          const int gs = gk ^ (row & 7) ^ ((gk >> 3) & 3);
          af[c][m] = *(const bf16x8*)(&inp_lds[row * 256 + gs * 8]);
        }
      __builtin_amdgcn_s_setprio(1);
      #pragma unroll
      for (int c = 0; c < 2; ++c)
        #pragma unroll
        for (int m = 0; m < 4; ++m)
          #pragma unroll
          for (int n = 0; n < 2; ++n)
            acc[c][m][n] = __builtin_amdgcn_mfma_f32_16x16x32_bf16(af[c][m], bfr[n], acc[c][m][n], 0, 0, 0);
      __builtin_amdgcn_s_setprio(0);
    }

    // ---- dot_ht from the LDS tile: wave's own 16 rows, 4 lanes/row ----
    {
      const int drow = wave * 16 + (lane >> 2);
      const int seg = lane & 3;
      float dsum = 0.f;
      #pragma unroll
      for (int j = 0; j < 8; ++j) {
        const int gidx = seg * 8 + ((j + drow) & 7);          // rotated
        const int gs = gidx ^ (drow & 7) ^ (seg & 3);         // same swizzle
        union { bf16x8 w; unsigned u[4]; } a;
        a.w = *(const bf16x8*)(&inp_lds[drow * 256 + gs * 8]);
        #pragma unroll
        for (int q = 0; q < 4; ++q) {
          union { unsigned u; float f; } lo, hi;
          lo.u = a.u[q] << 16;
          hi.u = a.u[q] & 0xFFFF0000u;
          dsum += lo.f + hi.f;
        }
      }
      dsum += __shfl_xor(dsum, 1);
      dsum += __shfl_xor(dsum, 2);
      if (seg == 0) dot_lds[drow] = dsum;
    }

    // epilogue: relu + b1, dot with w2, 16-lane reduce -> score_parts[wave][row]
    #pragma unroll
    for (int c = 0; c < 2; ++c) {
      #pragma unroll
      for (int m = 0; m < 4; ++m) {
        #pragma unroll
        for (int r = 0; r < 4; ++r) {
          float p = 0.f;
          #pragma unroll
          for (int n = 0; n < 2; ++n) {
            float hv = acc[c][m][n][r] + b1v[n];  // C/D: col=lane&15, row=(lane>>4)*4+r
            hv = hv > 0.f ? hv : 0.f;
            p += hv * w2v[n];
          }
          p += __shfl_xor(p, 1);
          p += __shfl_xor(p, 2);
          p += __shfl_xor(p, 4);
          p += __shfl_xor(p, 8);
          if (l15 == 0) score_parts[wave][c * 64 + m * 16 + lhi * 4 + r] = p;
        }
      }
    }
  }
  __syncthreads();

  // ---- P3: masked exp + partial sums -> per-(block,wave) ws slots ----
  if (wave < 2) {
    const int lrow = wave * 64 + lane;
    float sc = 0.f;
    #pragma unroll
    for (int w = 0; w < 8; ++w) sc += score_parts[w][lrow];
    const int item = history[b * NH + r0 + lrow];   // coalesced, L3-hot
    float e = (item != tgt_item) ? expf(sc) : 0.f;
    float ed = e * dot_lds[lrow];
    #pragma unroll
    for (int off = 32; off >= 1; off >>= 1) {
      e += __shfl_xor(e, off);
      ed += __shfl_xor(ed, off);
    }
    if (lane == 0) {
      part_se[blk * 2 + wave] = e;
      part_sd[blk * 2 + wave] = ed;
    }
  }
}

__global__ __launch_bounds__(256) void finalize(const float* __restrict__ part_se,
                                                const float* __restrict__ part_sd,
                                                float* __restrict__ out) {
  const int b = blockIdx.x * 256 + threadIdx.x;
  if (b < NB) {
    float se = 0.f, sd = 0.f;
    #pragma unroll
    for (int i = 0; i < BPB * 2; ++i) {
      se += part_se[b * BPB * 2 + i];
      sd += part_sd[b * BPB * 2 + i];
    }
    const float pred = (se > 0.f) ? (sd / sqrtf(se)) : 0.f;  // denom = sum^0.5
    out[b] = 1.f / (1.f + expf(-pred));
  }
}

extern "C" void kernel_launch(void* const* d_in, const int* in_sizes, int n_in,
                              void* d_out, int out_size, void* d_ws, size_t ws_size,
                              hipStream_t stream) {
  const int* history = (const int*)d_in[0];
  const int* target  = (const int*)d_in[1];
  const int* hregion = (const int*)d_in[2];
  const int* tregion = (const int*)d_in[3];
  const float* E_hist = (const float*)d_in[4];
  const float* E_targ = (const float*)d_in[5];
  const float* E_reg  = (const float*)d_in[6];
  const float* W1 = (const float*)d_in[7];
  const float* b1 = (const float*)d_in[8];
  const float* w2 = (const float*)d_in[9];
  float* out = (float*)d_out;

  char* p = (char*)d_ws;
  unsigned short* W1T = (unsigned short*)p;  p += (size_t)TWOD * HID * 2;   // 128 KB
  float* part_se = (float*)p;                p += (size_t)NBLK * 2 * 4;     // 16 KB
  float* part_sd = (float*)p;

  prep_w1t<<<16, 256, 0, stream>>>(W1, W1T);
  nais_main<<<NBLK, 512, 0, stream>>>(history, target, hregion, tregion,
                                      E_hist, E_targ, E_reg, W1T, b1, w2,
                                      part_se, part_sd);
  finalize<<<(NB + 255) / 256, 256, 0, stream>>>(part_se, part_sd, out);
}